// Round 9
// baseline (211.279 us; speedup 1.0000x reference)
//
#include <hip/hip_runtime.h>
#include <hip/hip_bf16.h>

#define IMG 1024
#define OUTW 1018
#define RS 36                  // output rows owned per strip
#define NSTRIP 29              // 29*36 = 1044 >= 1018
#define NXW 8                  // waves across width: 8*128 = 1024 cols
#define NBATCH 16
#define NWAVE (NBATCH * NSTRIP * NXW)  // 3712 waves, 1 per block
#define NSTEP (RS + 8)                 // 44 row-steps per strip
#define EPSF 2.2204460492503131e-16f
#define INV81 (1.0f / 81.0f)

// 9-sum windows at 2 offsets from positions 1..10 of a 12-array;
// bf16 ring storage so the vertical sliding-window subtract cancels exactly.
__device__ __forceinline__ void hsum2(const float* __restrict__ arr,
                                      float* __restrict__ wX,
                                      __hip_bfloat162* __restrict__ g) {
  float h0 = arr[1] + arr[2] + arr[3] + arr[4] + arr[5] + arr[6] + arr[7] +
             arr[8] + arr[9];
  float h1 = h0 - arr[1] + arr[10];
  __hip_bfloat162 pk = __float22bfloat162_rn(make_float2(h0, h1));
  float2 nw = __bfloat1622float2(pk);
  float2 od = __bfloat1622float2(*g);
  wX[0] += nw.x - od.x;
  wX[1] += nw.y - od.y;
  *g = pk;
}

__global__ __launch_bounds__(64, 4) void fused_kernel(
    const float* __restrict__ I, const float* __restrict__ J,
    double2* __restrict__ partial) {
  const int lane = threadIdx.x;
  const int wid = blockIdx.x;
  const int b = wid / (NSTRIP * NXW);
  const int rem = wid - b * (NSTRIP * NXW);
  const int strip = rem / NXW;
  const int xw = rem - strip * NXW;
  const int R0 = strip * RS;
  const int c0 = xw * 128 + 2 * lane;     // first owned column (even, <=1022)
  // 6 float2 loads per tensor covering cols c0-2 .. c0+9 (clamped addresses)
  int mo[6];
#pragma unroll
  for (int s = 0; s < 6; ++s) mo[s] = min(max(c0 - 2 + 2 * s, 0), IMG - 2);
  // per-position validity (col in [0,1023]); positions 0..11 = col c0-2+p
  bool ok[12];
#pragma unroll
  for (int p = 0; p < 12; ++p) {
    const int cp = c0 - 2 + p;
    ok[p] = (cp >= 0) && (cp <= IMG - 1);
  }
  const bool emit_ok = (c0 <= OUTW - 2);       // both ox=c0, c0+1 valid
  const bool dx2_ok = (c0 != IMG - 2);         // pair (c0+1, c0+2) valid
  const float* Ib = I + (size_t)b * (IMG * IMG);
  const float* Jb = J + (size_t)b * (IMG * IMG);

  // bf16 ring: 9 rows x 5 quantities x 1 bf162 = 45 VGPRs
  __hip_bfloat162 gI[9], gJ[9], gII[9], gJJ[9], gIJ[9];
  const __hip_bfloat162 z2 = __float22bfloat162_rn(make_float2(0.f, 0.f));
#pragma unroll
  for (int k = 0; k < 9; ++k) {
    gI[k] = z2; gJ[k] = z2; gII[k] = z2; gJJ[k] = z2; gIJ[k] = z2;
  }
  float wI[2] = {0,0}, wJ[2] = {0,0}, wII[2] = {0,0}, wJJ[2] = {0,0},
        wIJ[2] = {0,0};
  float prevI[2] = {0,0};
  float acc_cc = 0.f, acc_sm = 0.f;

  for (int tc = 0; tc < 5; ++tc) {
#pragma unroll
    for (int u = 0; u < 9; ++u) {
      const int t = tc * 9 + u;
      if (t < NSTEP) {
        const int r = R0 - 1 + t;      // input row
        float iw[12], jw[12];
        if (r >= 0 && r < IMG) {       // wave-uniform
          const float* rpI = Ib + ((size_t)r << 10);
          const float* rpJ = Jb + ((size_t)r << 10);
#pragma unroll
          for (int s = 0; s < 6; ++s) {
            const float2 a = *(const float2*)(rpI + mo[s]);
            const float2 c = *(const float2*)(rpJ + mo[s]);
            iw[2 * s]     = ok[2 * s]     ? a.x : 0.f;
            iw[2 * s + 1] = ok[2 * s + 1] ? a.y : 0.f;
            jw[2 * s]     = ok[2 * s]     ? c.x : 0.f;
            jw[2 * s + 1] = ok[2 * s + 1] ? c.y : 0.f;
          }
        } else {
#pragma unroll
          for (int p = 0; p < 12; ++p) { iw[p] = 0.f; jw[p] = 0.f; }
        }

        hsum2(iw, wI, &gI[u]);
        hsum2(jw, wJ, &gJ[u]);
        {
          float pr[12];
#pragma unroll
          for (int p = 1; p < 11; ++p) pr[p] = iw[p] * iw[p];
          hsum2(pr, wII, &gII[u]);
#pragma unroll
          for (int p = 1; p < 11; ++p) pr[p] = jw[p] * jw[p];
          hsum2(pr, wJJ, &gJJ[u]);
#pragma unroll
          for (int p = 1; p < 11; ++p) pr[p] = iw[p] * jw[p];
          hsum2(pr, wIJ, &gIJ[u]);
        }

        // smoothness dy: pairs (r-1, r) with r-1 owned by this strip
        if (r >= R0 + 1 && r <= R0 + RS && r <= IMG - 1) {   // uniform
          float d0 = iw[2] - prevI[0];
          float d1 = iw[3] - prevI[1];
          acc_sm = fmaf(d0, d0, acc_sm);
          acc_sm = fmaf(d1, d1, acc_sm);
        }
        // smoothness dx at owned rows: pairs (c0,c0+1), (c0+1,c0+2)
        if (r >= R0 && r <= R0 + RS - 1 && r <= IMG - 1) {   // uniform
          float d0 = iw[3] - iw[2];
          float d1 = dx2_ok ? (iw[4] - iw[3]) : 0.f;
          acc_sm = fmaf(d0, d0, acc_sm);
          acc_sm = fmaf(d1, d1, acc_sm);
        }
        prevI[0] = iw[2]; prevI[1] = iw[3];

        // emit output row oy = R0 + t - 8 once window complete
        if (t >= 8) {                                        // uniform
          const int oy = R0 + t - 8;
          if (oy < OUTW) {                                   // uniform
            if (emit_ok) {
#pragma unroll
              for (int q = 0; q < 2; ++q) {
                float cross = fmaf(-(wI[q] * wJ[q]), INV81, wIJ[q]);
                float iva   = fmaf(-(wI[q] * wI[q]), INV81, wII[q]);
                float jva   = fmaf(-(wJ[q] * wJ[q]), INV81, wJJ[q]);
                float den   = fmaf(iva, jva, EPSF);
                acc_cc += cross * cross * __builtin_amdgcn_rcpf(den);
              }
            }
          }
        }
      }
    }
  }

  // wave reduce (block == 1 wave)
  float vc = acc_cc, vs = acc_sm;
#pragma unroll
  for (int off = 32; off > 0; off >>= 1) {
    vc += __shfl_down(vc, off);
    vs += __shfl_down(vs, off);
  }
  if (lane == 0) partial[wid] = make_double2((double)vc, (double)vs);
}

__global__ __launch_bounds__(256) void fin_kernel(const double2* __restrict__ partial,
                                                  float* __restrict__ out) {
  double s_cc = 0.0, s_sm = 0.0;
  for (int i = threadIdx.x; i < NWAVE; i += 256) {
    double2 p = partial[i];
    s_cc += p.x; s_sm += p.y;
  }
#pragma unroll
  for (int off = 32; off > 0; off >>= 1) {
    s_cc += __shfl_down(s_cc, off);
    s_sm += __shfl_down(s_sm, off);
  }
  __shared__ double r1[4], r2[4];
  if ((threadIdx.x & 63) == 0) { r1[threadIdx.x >> 6] = s_cc; r2[threadIdx.x >> 6] = s_sm; }
  __syncthreads();
  if (threadIdx.x == 0) {
    const double cc = (r1[0] + r1[1] + r1[2] + r1[3]) /
                      (double)((size_t)NBATCH * OUTW * OUTW);
    const double sm = (r2[0] + r2[1] + r2[2] + r2[3]) /
                      (2.0 * (double)((size_t)NBATCH * IMG * (IMG - 1)));
    out[0] = (float)(-cc + 0.1 * sm);
  }
}

extern "C" void kernel_launch(void* const* d_in, const int* in_sizes, int n_in,
                              void* d_out, int out_size, void* d_ws, size_t ws_size,
                              hipStream_t stream) {
  const float* y  = (const float*)d_in[0];
  const float* yt = (const float*)d_in[1];
  float* out = (float*)d_out;
  double2* partial = (double2*)d_ws;
  fused_kernel<<<NWAVE, 64, 0, stream>>>(y, yt, partial);
  fin_kernel<<<1, 256, 0, stream>>>(partial, out);
}